// Round 14
// baseline (90.855 us; speedup 1.0000x reference)
//
#include <hip/hip_runtime.h>
#include <hip/hip_bf16.h>

#define B_  512
#define T_  256
#define C_  384
#define H_  64
#define SCALE_ 0.05103103630798287f   // 384^-0.5

typedef float f32x4  __attribute__((ext_vector_type(4)));
typedef short bf16x8 __attribute__((ext_vector_type(8)));
typedef short bf16x4 __attribute__((ext_vector_type(4)));

__device__ __forceinline__ unsigned short f2bf(float f) {
    union { float f; unsigned u; } v; v.f = f;
    unsigned r = v.u + 0x7FFFu + ((v.u >> 16) & 1u);   // RNE
    return (unsigned short)(r >> 16);
}
__device__ __forceinline__ unsigned cvt_pk_bf16(float lo, float hi) {
    unsigned r;
    asm("v_cvt_pk_bf16_f32 %0, %1, %2" : "=v"(r) : "v"(lo), "v"(hi));
    return r;
}
// XOR-swizzled [R][64]-short tile index (row = 128 B = 8 x 16B blocks).
__device__ __forceinline__ int swz64(int row, int col) {
    return row * 64 + (((col >> 3) ^ (row & 7)) << 3) + (col & 7);
}
// Wl[192][392] swizzle: 16B-block index XOR'd by (row&7) and bit2 by (row>>3)&1.
__device__ __forceinline__ int swzW(int row, int kblk) {
    return row * 392 + (((kblk ^ (row & 7) ^ (((row >> 3) & 1) << 2))) << 3);
}

// LDS (shorts): smem[75264] = 150528 B.
//  Phase-1 view: Wl[192][392] (full W^T resident, bf16, swzW swizzle)
//  Post-phase-1 aliases:
//    Ks [0,16384)       [256][64] swz64
//    Qs [16384,32768)   [256][64] swz64
//    Vt [32768,49664)   [64][264] (V^T rows h, cols t)
//    Pb [49664,70144)   16 waves x 2x[16][40] P^T dbuf scratch
//
// Stage: coalesced W row-reads (256B/wave-instr), k-pairs packed b32, swzW
// scatter (~2-way). Phase 1 (R7-proven): BARRIER-FREE, wave grid 8 row-bands x
// 2 col-halves -> 12 B-frag b128 reads per wave-chunk (half of R9's 24).
// Phase 2: R9-verbatim online-softmax S^T pipeline (qf from block-shared Qs).
__global__ __launch_bounds__(1024, 4) void att_head_kernel(
    const float* __restrict__ x,  const float* __restrict__ Wk,
    const float* __restrict__ Wq, const float* __restrict__ Wv,
    float* __restrict__ out)
{
    __shared__ __align__(16) short smem[75264];
    short* const Ks = smem;
    short* const Qs = smem + 16384;
    short* const Vt = smem + 32768;
    short* const Pb = smem + 49664;

    const int tid  = threadIdx.x;
    const int b    = blockIdx.x;
    const int w    = tid >> 6;        // 0..15
    const int lane = tid & 63;
    const int g    = lane >> 4;
    const int i    = lane & 15;
    const int wr   = w >> 1;          // row band: rows [32wr, 32wr+32)
    const int wc   = w & 1;           // col half: cols [96wc, 96wc+96)

    const float* xb = x + (size_t)b * T_ * C_;
    const float* Wm[3] = { Wk, Wq, Wv };

    // ---- Stage W^T -> Wl once: coalesced dword reads, b32 swzW writes ----
    {
        const int wp = (w + (lane >> 2)) & 15;   // lane-rotated k-group
        #pragma unroll
        for (int m = 0; m < 3; m++) {
            const int row = m * 64 + lane;
            #pragma unroll
            for (int t = 0; t < 12; t++) {
                const int k0 = 32 * t + 2 * wp;  // even k
                const float a0 = Wm[m][(size_t)k0 * H_ + lane];
                const float a1 = Wm[m][(size_t)(k0 + 1) * H_ + lane];
                *(unsigned*)&smem[swzW(row, k0 >> 3) + (k0 & 7)] = cvt_pk_bf16(a0, a1);
            }
        }
    }
    asm volatile("s_waitcnt lgkmcnt(0)\n\ts_barrier" ::: "memory");

    // ---- Phase 1 (R7-proven): 6 chunks of k=64, NO barriers ----
    const float* xs0 = xb + (size_t)(32 * wr + i) * C_ + g * 8;   // strip 0 rows
    const float* xs1 = xs0 + 16 * C_;                             // strip 1 rows

    f32x4 accP[2][6];
    #pragma unroll
    for (int m = 0; m < 2; m++)
        #pragma unroll
        for (int nb = 0; nb < 6; nb++) accP[m][nb] = f32x4{0.f, 0.f, 0.f, 0.f};

    const int ixor = (i & 7) ^ (((i >> 3) & 1) << 2);   // read-side swzW lane term

    #pragma unroll 2
    for (int j = 0; j < 6; j++) {
        float4 xv[2][4];
        #pragma unroll
        for (int ks = 0; ks < 2; ks++) {
            xv[0][2 * ks]     = *(const float4*)(xs0 + 64 * j + 32 * ks);
            xv[0][2 * ks + 1] = *(const float4*)(xs0 + 64 * j + 32 * ks + 4);
            xv[1][2 * ks]     = *(const float4*)(xs1 + 64 * j + 32 * ks);
            xv[1][2 * ks + 1] = *(const float4*)(xs1 + 64 * j + 32 * ks + 4);
        }
        bf16x8 afs[2][2];
        #pragma unroll
        for (int m = 0; m < 2; m++)
            #pragma unroll
            for (int ks = 0; ks < 2; ks++) {
                union { bf16x8 v; unsigned u[4]; } a;
                a.u[0] = cvt_pk_bf16(xv[m][2 * ks].x,     xv[m][2 * ks].y);
                a.u[1] = cvt_pk_bf16(xv[m][2 * ks].z,     xv[m][2 * ks].w);
                a.u[2] = cvt_pk_bf16(xv[m][2 * ks + 1].x, xv[m][2 * ks + 1].y);
                a.u[3] = cvt_pk_bf16(xv[m][2 * ks + 1].z, xv[m][2 * ks + 1].w);
                afs[m][ks] = a.v;
            }
        #pragma unroll
        for (int nb = 0; nb < 6; nb++) {
            const int row   = 96 * wc + 16 * nb + i;
            const int rbase = row * 392;
            #pragma unroll
            for (int ks = 0; ks < 2; ks++) {
                const int blk = (8 * j + 4 * ks + g) ^ ixor;
                const bf16x8 bfr = *(const bf16x8*)&smem[rbase + (blk << 3)];
                accP[0][nb] = __builtin_amdgcn_mfma_f32_16x16x32_bf16(afs[0][ks], bfr, accP[0][nb], 0, 0, 0);
                accP[1][nb] = __builtin_amdgcn_mfma_f32_16x16x32_bf16(afs[1][ks], bfr, accP[1][nb], 0, 0, 0);
            }
        }
    }
    // all waves must finish reading Wl before K/Q/V overwrite it
    asm volatile("s_waitcnt lgkmcnt(0)\n\ts_barrier" ::: "memory");

    // ---- Epilogue (R7/R10-proven): scatter K,Q (b16, swz64) and V (b64) ----
    #pragma unroll
    for (int m = 0; m < 2; m++) {
        const int row0 = 32 * wr + 16 * m + 4 * g;
        #pragma unroll
        for (int nb = 0; nb < 6; nb++) {
            const int gc = 96 * wc + 16 * nb;   // wave-uniform
            if (gc < 64) {
                #pragma unroll
                for (int r = 0; r < 4; r++)
                    Ks[swz64(row0 + r, gc + i)] = (short)f2bf(accP[m][nb][r]);
            } else if (gc < 128) {
                #pragma unroll
                for (int r = 0; r < 4; r++)
                    Qs[swz64(row0 + r, gc - 64 + i)] = (short)f2bf(accP[m][nb][r]);
            } else {
                bf16x4 pk;
                #pragma unroll
                for (int r = 0; r < 4; r++) pk[r] = (short)f2bf(accP[m][nb][r]);
                *(bf16x4*)&Vt[(gc - 128 + i) * 264 + row0] = pk;
            }
        }
    }
    asm volatile("s_waitcnt lgkmcnt(0)\n\ts_barrier" ::: "memory");

    // ---- Phase 2 (R9-verbatim): online causal attention, S^T ----
    const int rb = 16 * w;
    bf16x8 qf[2];
    #pragma unroll
    for (int ks = 0; ks < 2; ks++)
        qf[ks] = *(const bf16x8*)&Qs[(rb + i) * 64 + (((4 * ks + g) ^ (i & 7)) << 3)];

    short* const myP = Pb + w * 1280;    // two [16][40] buffers
    const float NEG_INF = -__builtin_inff();
    float mrun = NEG_INF, lrun = 0.f;
    f32x4 accO[4];
    #pragma unroll
    for (int ht = 0; ht < 4; ht++) accO[ht] = f32x4{0.f, 0.f, 0.f, 0.f};

    auto PVADD = [&](int bufsel, int ck) {
        const bf16x8 pf = *(const bf16x8*)&myP[bufsel * 640 + i * 40 + 8 * g];
        #pragma unroll
        for (int ht = 0; ht < 4; ht++) {
            const bf16x8 vf = *(const bf16x8*)&Vt[(16 * ht + i) * 264 + 32 * ck + 8 * g];
            accO[ht] = __builtin_amdgcn_mfma_f32_16x16x32_bf16(vf, pf, accO[ht], 0, 0, 0);
        }
    };

    const int npair = w >> 1;
    #pragma unroll
    for (int p = 0; p < 8; p++) {
        if (p <= npair) {                // wave-uniform
            f32x4 sA[2];
            sA[0] = f32x4{0.f, 0.f, 0.f, 0.f};
            sA[1] = f32x4{0.f, 0.f, 0.f, 0.f};
            #pragma unroll
            for (int s = 0; s < 2; s++) {
                const int nt = 2 * p + s;
                if (nt <= w) {           // wave-uniform
                    #pragma unroll
                    for (int ks = 0; ks < 2; ks++) {
                        const bf16x8 kfr = *(const bf16x8*)&Ks[(16 * nt + i) * 64 +
                                (((4 * ks + g) ^ (i & 7)) << 3)];
                        sA[s] = __builtin_amdgcn_mfma_f32_16x16x32_bf16(kfr, qf[ks], sA[s], 0, 0, 0);
                    }
                }
            }
            if (p > 0) PVADD((p - 1) & 1, p - 1);   // pipelined PV of prev pair

            float mt = NEG_INF;
            #pragma unroll
            for (int s = 0; s < 2; s++)
                #pragma unroll
                for (int r = 0; r < 4; r++) {
                    const int kv = 16 * (2 * p + s) + 4 * g + r;
                    const bool ok = (2 * p + s <= w) && (kv <= rb + i);
                    const float v = ok ? sA[s][r] * SCALE_ : NEG_INF;
                    sA[s][r] = v;
                    mt = fmaxf(mt, v);
                }
            mt = fmaxf(mt, __shfl_xor(mt, 16, 64));
            mt = fmaxf(mt, __shfl_xor(mt, 32, 64));

            if (!__all(mt <= mrun + 8.0f)) {        // defer-max (THR=8)
                const float mnew = fmaxf(mrun, mt);
                const float f = __expf(mrun - mnew);
                mrun = mnew; lrun *= f;
                #pragma unroll
                for (int ht = 0; ht < 4; ht++)
                    #pragma unroll
                    for (int r = 0; r < 4; r++) accO[ht][r] *= f;
            }
            #pragma unroll
            for (int s = 0; s < 2; s++) {
                const float p0 = __expf(sA[s][0] - mrun);
                const float p1 = __expf(sA[s][1] - mrun);
                const float p2 = __expf(sA[s][2] - mrun);
                const float p3 = __expf(sA[s][3] - mrun);
                lrun += (p0 + p1) + (p2 + p3);
                union { bf16x4 v; unsigned u[2]; } pk;
                pk.u[0] = cvt_pk_bf16(p0, p1);
                pk.u[1] = cvt_pk_bf16(p2, p3);
                *(bf16x4*)&myP[(p & 1) * 640 + i * 40 + 16 * s + 4 * g] = pk.v;
            }
        }
    }
    PVADD(npair & 1, npair);             // drain last pair

    lrun += __shfl_xor(lrun, 16, 64);
    lrun += __shfl_xor(lrun, 32, 64);
    const float inv = 1.f / lrun;

    float* orow = out + ((size_t)b * T_ + rb + i) * H_;
    #pragma unroll
    for (int ht = 0; ht < 4; ht++) {
        float4 o;
        o.x = accO[ht][0] * inv;
        o.y = accO[ht][1] * inv;
        o.z = accO[ht][2] * inv;
        o.w = accO[ht][3] * inv;
        *(float4*)&orow[16 * ht + 4 * g] = o;
    }
}

extern "C" void kernel_launch(void* const* d_in, const int* in_sizes, int n_in,
                              void* d_out, int out_size, void* d_ws, size_t ws_size,
                              hipStream_t stream) {
    const float* x  = (const float*)d_in[0];
    const float* Wk = (const float*)d_in[1];
    const float* Wq = (const float*)d_in[2];
    const float* Wv = (const float*)d_in[3];
    float* out = (float*)d_out;
    (void)d_ws; (void)ws_size; (void)in_sizes; (void)n_in; (void)out_size;
    att_head_kernel<<<dim3(B_), dim3(1024), 0, stream>>>(x, Wk, Wq, Wv, out);
}

// Round 16
// 59.086 us; speedup vs baseline: 1.5377x; 1.5377x over previous
//
#include <hip/hip_runtime.h>
#include <hip/hip_bf16.h>

#define B_  512
#define T_  256
#define C_  384
#define H_  64
#define SCALE_ 0.05103103630798287f   // 384^-0.5

typedef float f32x4  __attribute__((ext_vector_type(4)));
typedef short bf16x8 __attribute__((ext_vector_type(8)));
typedef short bf16x4 __attribute__((ext_vector_type(4)));

__device__ __forceinline__ unsigned short f2bf(float f) {
    union { float f; unsigned u; } v; v.f = f;
    unsigned r = v.u + 0x7FFFu + ((v.u >> 16) & 1u);   // RNE
    return (unsigned short)(r >> 16);
}
__device__ __forceinline__ unsigned cvt_pk_bf16(float lo, float hi) {
    unsigned r;
    asm("v_cvt_pk_bf16_f32 %0, %1, %2" : "=v"(r) : "v"(lo), "v"(hi));
    return r;
}
// XOR-swizzled [R][64]-short tile index (row = 128 B = 8 x 16B blocks).
__device__ __forceinline__ int swz64(int row, int col) {
    return row * 64 + (((col >> 3) ^ (row & 7)) << 3) + (col & 7);
}

// LDS (shorts): smem[33280] = 66560 B  ->  TWO workgroups fit per CU (2x66560 =
// 133120 < 160K), doubling the occupancy cap vs R9 (was 107.5 KB, 1 WG/CU).
//  Phase-1: wst0 [0,12288), wst1 [12288,24576)  (W^T k-chunk double buffer)
//  Phase-2 (alias, written after last wst read + barrier):
//    Ks[256][64] swz64  [0,     16384)
//    Vt[64][264]        [16384, 33280)   (V^T: rows h, cols t, +8 pad)
//
// Phase 1: R9-verbatim (proven 57.5us). Phase 2: S^T online softmax per TILE
// PAIR; P redistributed to the K=32 PV B-operand IN REGISTERS via
// cvt_pk + v_permlane32_swap + shfl_xor(16) (R11-proven primitives, builtin
// MFMA only) -> no P LDS buffer, no lgkmcnt serialization.
__global__ __launch_bounds__(1024, 4) void att_head_kernel(
    const float* __restrict__ x,  const float* __restrict__ Wk,
    const float* __restrict__ Wq, const float* __restrict__ Wv,
    float* __restrict__ out)
{
    __shared__ __align__(16) short smem[33280];
    short* const wst0 = smem;
    short* const wst1 = smem + 12288;
    short* const Ks   = smem;            // alias (live after phase 1)
    short* const Vt   = smem + 16384;

    const int tid  = threadIdx.x;
    const int b    = blockIdx.x;
    const int w    = tid >> 6;        // 0..15
    const int lane = tid & 63;
    const int g    = lane >> 4;
    const int i    = lane & 15;
    const int rb   = 16 * w;          // this wave's Q-row strip base

    const float* xb = x + (size_t)b * T_ * C_;
    const float* Wm[3] = { Wk, Wq, Wv };

    f32x4 accP[12];
    #pragma unroll
    for (int nb = 0; nb < 12; nb++) accP[nb] = f32x4{0.f, 0.f, 0.f, 0.f};

    // per-lane global base for this wave's A-rows
    const float* xrow = xb + (size_t)(rb + i) * C_ + g * 8;

    // ---- W staging (R9): thread (w, lane): rows m*64+lane, k-quad w, swizzled b64 ----
    auto stageW = [&](int kc, short* buf) {
        #pragma unroll
        for (int m = 0; m < 3; m++) {
            const float* Wp = Wm[m] + (size_t)(kc + w * 4) * H_ + lane;
            bf16x4 pk;
            #pragma unroll
            for (int jj = 0; jj < 4; jj++) pk[jj] = (short)f2bf(Wp[jj * H_]);
            const int row = m * 64 + lane;
            const int k0  = w * 4;
            *(bf16x4*)&buf[row * 64 + (((k0 >> 3) ^ (row & 7)) << 3) + (k0 & 7)] = pk;
        }
    };

    // ---------------- Phase 1 (R9 verbatim): 6 chunks of k=64 ----------------
    float4 xr[2][4];
    #pragma unroll
    for (int ks = 0; ks < 2; ks++)
        #pragma unroll
        for (int h = 0; h < 2; h++)
            xr[0][ks * 2 + h] = *(const float4*)(xrow + ks * 32 + h * 4);
    stageW(0, wst0);
    asm volatile("s_waitcnt lgkmcnt(0)\n\ts_barrier" ::: "memory");

    #pragma unroll
    for (int j = 0; j < 6; j++) {
        const int par = j & 1;
        short* cur = par ? wst1 : wst0;
        if (j < 5) {
            #pragma unroll
            for (int ks = 0; ks < 2; ks++)
                #pragma unroll
                for (int h = 0; h < 2; h++)
                    xr[par ^ 1][ks * 2 + h] = *(const float4*)(xrow + (j + 1) * 64 + ks * 32 + h * 4);
            stageW((j + 1) * 64, par ? wst0 : wst1);
        }
        bf16x8 afs[2];
        #pragma unroll
        for (int ks = 0; ks < 2; ks++)
            #pragma unroll
            for (int h = 0; h < 2; h++) {
                const float4 v = xr[par][ks * 2 + h];
                afs[ks][h * 4 + 0] = (short)f2bf(v.x);
                afs[ks][h * 4 + 1] = (short)f2bf(v.y);
                afs[ks][h * 4 + 2] = (short)f2bf(v.z);
                afs[ks][h * 4 + 3] = (short)f2bf(v.w);
            }
        #pragma unroll
        for (int nb = 0; nb < 12; nb++) {
            #pragma unroll
            for (int ks = 0; ks < 2; ks++) {
                const int brow = nb * 16 + i;
                const bf16x8 bfr = *(const bf16x8*)&cur[brow * 64 + (((ks * 4 + g) ^ (i & 7)) << 3)];
                accP[nb] = __builtin_amdgcn_mfma_f32_16x16x32_bf16(afs[ks], bfr, accP[nb], 0, 0, 0);
            }
        }
        asm volatile("s_waitcnt lgkmcnt(0)\n\ts_barrier" ::: "memory");
    }
    // wst dead from here (barrier above drained all reads)

    // ---------------- Epilogue (R9 verbatim) ----------------
    // (1) Q -> own Ks slice (rows rb..rb+16), wave-local transpose
    #pragma unroll
    for (int nb = 0; nb < 4; nb++)
        #pragma unroll
        for (int r = 0; r < 4; r++)
            Ks[swz64(rb + 4 * g + r, 16 * nb + i)] = (short)f2bf(accP[4 + nb][r]);
    asm volatile("s_waitcnt lgkmcnt(0)" ::: "memory");
    bf16x8 qf[2];
    #pragma unroll
    for (int ks = 0; ks < 2; ks++)
        qf[ks] = *(const bf16x8*)&Ks[(rb + i) * 64 + (((4 * ks + g) ^ (i & 7)) << 3)];
    asm volatile("s_waitcnt lgkmcnt(0)" ::: "memory");   // qf landed before overwrite
    // (2) K -> same slice (b16 scatter)
    #pragma unroll
    for (int nb = 0; nb < 4; nb++)
        #pragma unroll
        for (int r = 0; r < 4; r++)
            Ks[swz64(rb + 4 * g + r, 16 * nb + i)] = (short)f2bf(accP[nb][r]);
    // (3) V -> Vt[h][t], packed b64 (r-consecutive t)
    #pragma unroll
    for (int nb = 0; nb < 4; nb++) {
        bf16x4 pk;
        #pragma unroll
        for (int r = 0; r < 4; r++) pk[r] = (short)f2bf(accP[8 + nb][r]);
        *(bf16x4*)&Vt[(16 * nb + i) * 264 + rb + 4 * g] = pk;
    }
    asm volatile("s_waitcnt lgkmcnt(0)\n\ts_barrier" ::: "memory");

    // ---------------- Phase 2: online attention, in-register P (no P LDS) --------
    const float NEG_INF = -__builtin_inff();
    float mrun = NEG_INF, lrun = 0.f;
    f32x4 accO[4];
    #pragma unroll
    for (int ht = 0; ht < 4; ht++) accO[ht] = f32x4{0.f, 0.f, 0.f, 0.f};

    const bool godd = (g & 1) != 0;
    const int npair = w >> 1;            // last pair index; pair p = tiles 2p, 2p+1
    #pragma unroll
    for (int p = 0; p < 8; p++) {
        if (p <= npair) {                // wave-uniform
            // QK^T (S^T tiles): lane holds (kv = 16*(2p+s)+4g+r, q = rb+i)
            f32x4 sA[2];
            sA[0] = f32x4{0.f, 0.f, 0.f, 0.f};
            sA[1] = f32x4{0.f, 0.f, 0.f, 0.f};
            #pragma unroll
            for (int s = 0; s < 2; s++) {
                const int nt = 2 * p + s;
                if (nt <= w) {           // wave-uniform
                    #pragma unroll
                    for (int ks = 0; ks < 2; ks++) {
                        const bf16x8 kfr = *(const bf16x8*)&Ks[(16 * nt + i) * 64 +
                                (((4 * ks + g) ^ (i & 7)) << 3)];
                        sA[s] = __builtin_amdgcn_mfma_f32_16x16x32_bf16(kfr, qf[ks], sA[s], 0, 0, 0);
                    }
                }
            }
            // scale + causal mask + pair max
            float mt = NEG_INF;
            #pragma unroll
            for (int s = 0; s < 2; s++)
                #pragma unroll
                for (int r = 0; r < 4; r++) {
                    const int kv = 16 * (2 * p + s) + 4 * g + r;
                    const bool ok = (2 * p + s <= w) && (kv <= rb + i);
                    const float v = ok ? sA[s][r] * SCALE_ : NEG_INF;
                    sA[s][r] = v;
                    mt = fmaxf(mt, v);
                }
            mt = fmaxf(mt, __shfl_xor(mt, 16, 64));
            mt = fmaxf(mt, __shfl_xor(mt, 32, 64));

            if (!__all(mt <= mrun + 8.0f)) {        // defer-max (THR=8)
                const float mnew = fmaxf(mrun, mt);
                const float f = __expf(mrun - mnew);
                mrun = mnew; lrun *= f;
                #pragma unroll
                for (int ht = 0; ht < 4; ht++)
                    #pragma unroll
                    for (int r = 0; r < 4; r++) accO[ht][r] *= f;
            }
            // exp + l-accum, pack per-tile words
            float e0[4], e1[4];
            #pragma unroll
            for (int r = 0; r < 4; r++) {
                e0[r] = __expf(sA[0][r] - mrun);
                e1[r] = __expf(sA[1][r] - mrun);
                lrun += e0[r] + e1[r];
            }
            unsigned a0 = cvt_pk_bf16(e0[0], e0[1]);
            unsigned a1 = cvt_pk_bf16(e0[2], e0[3]);
            unsigned b0 = cvt_pk_bf16(e1[0], e1[1]);
            unsigned b1 = cvt_pk_bf16(e1[2], e1[3]);
            // redistribute: target lane(g,i) word e holds P[kv32=8g+2e..][q=i]
            asm volatile("v_permlane32_swap_b32 %0, %1" : "+v"(a0), "+v"(b0));
            asm volatile("v_permlane32_swap_b32 %0, %1" : "+v"(a1), "+v"(b1));
            const unsigned sa0 = __shfl_xor(a0, 16, 64);
            const unsigned sa1 = __shfl_xor(a1, 16, 64);
            const unsigned sb0 = __shfl_xor(b0, 16, 64);
            const unsigned sb1 = __shfl_xor(b1, 16, 64);
            union { bf16x8 v; unsigned u[4]; } pfB;
            pfB.u[0] = godd ? sb0 : a0;
            pfB.u[1] = godd ? sb1 : a1;
            pfB.u[2] = godd ? b0  : sa0;
            pfB.u[3] = godd ? b1  : sa1;

            // PV (K=32): accO[ht] += V^T(h=16ht+i, kv32=8g+e) x P
            #pragma unroll
            for (int ht = 0; ht < 4; ht++) {
                const bf16x8 vf = *(const bf16x8*)&Vt[(16 * ht + i) * 264 + 32 * p + 8 * g];
                accO[ht] = __builtin_amdgcn_mfma_f32_16x16x32_bf16(vf, pfB.v, accO[ht], 0, 0, 0);
            }
        }
    }

    // final denominator (sum across the 4 g-lanes of column q)
    lrun += __shfl_xor(lrun, 16, 64);
    lrun += __shfl_xor(lrun, 32, 64);
    const float inv = 1.f / lrun;

    // store O^T: lane holds (h = 16ht+4g+r, q = rb+i) -> float4 per ht
    float* orow = out + ((size_t)b * T_ + rb + i) * H_;
    #pragma unroll
    for (int ht = 0; ht < 4; ht++) {
        float4 o;
        o.x = accO[ht][0] * inv;
        o.y = accO[ht][1] * inv;
        o.z = accO[ht][2] * inv;
        o.w = accO[ht][3] * inv;
        *(float4*)&orow[16 * ht + 4 * g] = o;
    }
}

extern "C" void kernel_launch(void* const* d_in, const int* in_sizes, int n_in,
                              void* d_out, int out_size, void* d_ws, size_t ws_size,
                              hipStream_t stream) {
    const float* x  = (const float*)d_in[0];
    const float* Wk = (const float*)d_in[1];
    const float* Wq = (const float*)d_in[2];
    const float* Wv = (const float*)d_in[3];
    float* out = (float*)d_out;
    (void)d_ws; (void)ws_size; (void)in_sizes; (void)n_in; (void)out_size;
    att_head_kernel<<<dim3(B_), dim3(1024), 0, stream>>>(x, Wk, Wq, Wv, out);
}

// Round 17
// 56.886 us; speedup vs baseline: 1.5971x; 1.0387x over previous
//
#include <hip/hip_runtime.h>
#include <hip/hip_bf16.h>

#define B_  512
#define T_  256
#define C_  384
#define H_  64
#define SCALE_ 0.05103103630798287f   // 384^-0.5

typedef float f32x4  __attribute__((ext_vector_type(4)));
typedef short bf16x8 __attribute__((ext_vector_type(8)));
typedef short bf16x4 __attribute__((ext_vector_type(4)));

__device__ __forceinline__ unsigned short f2bf(float f) {
    union { float f; unsigned u; } v; v.f = f;
    unsigned r = v.u + 0x7FFFu + ((v.u >> 16) & 1u);   // RNE
    return (unsigned short)(r >> 16);
}
__device__ __forceinline__ unsigned cvt_pk_bf16(float lo, float hi) {
    unsigned r;
    asm("v_cvt_pk_bf16_f32 %0, %1, %2" : "=v"(r) : "v"(lo), "v"(hi));
    return r;
}
// XOR-swizzled [R][64]-short tile index (row = 128 B = 8 x 16B blocks).
__device__ __forceinline__ int swz64(int row, int col) {
    return row * 64 + (((col >> 3) ^ (row & 7)) << 3) + (col & 7);
}

// LDS (shorts): smem[73728] = 147456 B.
//  Phase-1: wst[j] at j*12288, j=0..5 — ALL SIX W^T k=64 chunks resident, each
//  [192][64] with the R9-proven swizzle. Staged once, ONE barrier, then phase 1
//  is completely barrier-free (buffers read-only; waves drift independently).
//  Phase-2 (alias, written after the single post-phase-1 barrier):
//    Ks[256][64] swz64   [0,     16384)
//    Vt[64][264]         [16384, 33280)
//    Pb 16 x 2x[16][40]  [33280, 53760)
//
// Barriers: 3 total (R9 had 14). Everything else R9-verbatim (proven 57.5us).
__global__ __launch_bounds__(1024, 4) void att_head_kernel(
    const float* __restrict__ x,  const float* __restrict__ Wk,
    const float* __restrict__ Wq, const float* __restrict__ Wv,
    float* __restrict__ out)
{
    __shared__ __align__(16) short smem[73728];
    short* const Ks = smem;              // alias (live after phase 1)
    short* const Vt = smem + 16384;
    short* const Pb = smem + 33280;

    const int tid  = threadIdx.x;
    const int b    = blockIdx.x;
    const int w    = tid >> 6;        // 0..15
    const int lane = tid & 63;
    const int g    = lane >> 4;
    const int i    = lane & 15;
    const int rb   = 16 * w;          // this wave's Q-row strip base

    const float* xb = x + (size_t)b * T_ * C_;
    const float* Wm[3] = { Wk, Wq, Wv };

    f32x4 accP[12];
    #pragma unroll
    for (int nb = 0; nb < 12; nb++) accP[nb] = f32x4{0.f, 0.f, 0.f, 0.f};

    // per-lane global base for this wave's A-rows
    const float* xrow = xb + (size_t)(rb + i) * C_ + g * 8;

    // ---- Stage ALL 6 W^T chunks (R9 write pattern, software-pipelined) ----
    {
        float wfa[12], wfb[12];
        auto loadWchunk = [&](int j, float* dst) {
            #pragma unroll
            for (int m = 0; m < 3; m++) {
                const float* Wp = Wm[m] + (size_t)(j * 64 + w * 4) * H_ + lane;
                #pragma unroll
                for (int jj = 0; jj < 4; jj++) dst[m * 4 + jj] = Wp[jj * H_];
            }
        };
        auto writeWchunk = [&](int j, const float* src) {
            short* buf = smem + j * 12288;
            #pragma unroll
            for (int m = 0; m < 3; m++) {
                union { unsigned u; short s[2]; } p0, p1;
                p0.u = cvt_pk_bf16(src[4 * m + 0], src[4 * m + 1]);
                p1.u = cvt_pk_bf16(src[4 * m + 2], src[4 * m + 3]);
                bf16x4 pk;
                pk[0] = p0.s[0]; pk[1] = p0.s[1]; pk[2] = p1.s[0]; pk[3] = p1.s[1];
                const int row = m * 64 + lane;
                const int k0  = w * 4;
                *(bf16x4*)&buf[row * 64 + (((k0 >> 3) ^ (row & 7)) << 3) + (k0 & 7)] = pk;
            }
        };
        loadWchunk(0, wfa);
        #pragma unroll
        for (int j = 0; j < 6; j++) {
            float* curW = (j & 1) ? wfb : wfa;
            float* nxtW = (j & 1) ? wfa : wfb;
            if (j < 5) loadWchunk(j + 1, nxtW);   // issue next loads first (T14)
            writeWchunk(j, curW);
        }
    }
    // prefetch x chunk 0 (lands under the barrier wait)
    float4 xr[2][4];
    #pragma unroll
    for (int ks = 0; ks < 2; ks++)
        #pragma unroll
        for (int h = 0; h < 2; h++)
            xr[0][ks * 2 + h] = *(const float4*)(xrow + ks * 32 + h * 4);
    asm volatile("s_waitcnt lgkmcnt(0)\n\ts_barrier" ::: "memory");   // W^T resident

    // ---------------- Phase 1: 6 chunks of k=64, BARRIER-FREE ----------------
    #pragma unroll
    for (int j = 0; j < 6; j++) {
        const int par = j & 1;
        const short* cur = smem + j * 12288;
        if (j < 5) {
            #pragma unroll
            for (int ks = 0; ks < 2; ks++)
                #pragma unroll
                for (int h = 0; h < 2; h++)
                    xr[par ^ 1][ks * 2 + h] = *(const float4*)(xrow + (j + 1) * 64 + ks * 32 + h * 4);
        }
        bf16x8 afs[2];
        #pragma unroll
        for (int ks = 0; ks < 2; ks++)
            #pragma unroll
            for (int h = 0; h < 2; h++) {
                const float4 v = xr[par][ks * 2 + h];
                afs[ks][h * 4 + 0] = (short)f2bf(v.x);
                afs[ks][h * 4 + 1] = (short)f2bf(v.y);
                afs[ks][h * 4 + 2] = (short)f2bf(v.z);
                afs[ks][h * 4 + 3] = (short)f2bf(v.w);
            }
        #pragma unroll
        for (int nb = 0; nb < 12; nb++) {
            #pragma unroll
            for (int ks = 0; ks < 2; ks++) {
                const int brow = nb * 16 + i;
                const bf16x8 bfr = *(const bf16x8*)&cur[brow * 64 + (((ks * 4 + g) ^ (i & 7)) << 3)];
                accP[nb] = __builtin_amdgcn_mfma_f32_16x16x32_bf16(afs[ks], bfr, accP[nb], 0, 0, 0);
            }
        }
    }
    // all waves must finish reading wst before K/Q/V overwrite it
    asm volatile("s_waitcnt lgkmcnt(0)\n\ts_barrier" ::: "memory");

    // ---------------- Epilogue (R9 verbatim) ----------------
    // (1) Q -> own Ks slice (rows rb..rb+16), wave-local transpose
    #pragma unroll
    for (int nb = 0; nb < 4; nb++)
        #pragma unroll
        for (int r = 0; r < 4; r++)
            Ks[swz64(rb + 4 * g + r, 16 * nb + i)] = (short)f2bf(accP[4 + nb][r]);
    asm volatile("s_waitcnt lgkmcnt(0)" ::: "memory");
    bf16x8 qf[2];
    #pragma unroll
    for (int ks = 0; ks < 2; ks++)
        qf[ks] = *(const bf16x8*)&Ks[(rb + i) * 64 + (((4 * ks + g) ^ (i & 7)) << 3)];
    asm volatile("s_waitcnt lgkmcnt(0)" ::: "memory");   // qf landed before overwrite
    // (2) K -> same slice (b16 scatter)
    #pragma unroll
    for (int nb = 0; nb < 4; nb++)
        #pragma unroll
        for (int r = 0; r < 4; r++)
            Ks[swz64(rb + 4 * g + r, 16 * nb + i)] = (short)f2bf(accP[nb][r]);
    // (3) V -> Vt[h][t], packed b64 (r-consecutive t)
    #pragma unroll
    for (int nb = 0; nb < 4; nb++) {
        bf16x4 pk;
        #pragma unroll
        for (int r = 0; r < 4; r++) pk[r] = (short)f2bf(accP[8 + nb][r]);
        *(bf16x4*)&Vt[(16 * nb + i) * 264 + rb + 4 * g] = pk;
    }
    asm volatile("s_waitcnt lgkmcnt(0)\n\ts_barrier" ::: "memory");

    // ---------------- Phase 2 (R9 verbatim): online causal attention, S^T --------
    short* const myP = Pb + w * 1280;    // two [16][40] buffers
    const float NEG_INF = -__builtin_inff();
    float mrun = NEG_INF, lrun = 0.f;
    f32x4 accO[4];
    #pragma unroll
    for (int ht = 0; ht < 4; ht++) accO[ht] = f32x4{0.f, 0.f, 0.f, 0.f};

    auto PVADD = [&](int bufsel, int ck) {
        const bf16x8 pf = *(const bf16x8*)&myP[bufsel * 640 + i * 40 + 8 * g];
        #pragma unroll
        for (int ht = 0; ht < 4; ht++) {
            const bf16x8 vf = *(const bf16x8*)&Vt[(16 * ht + i) * 264 + 32 * ck + 8 * g];
            accO[ht] = __builtin_amdgcn_mfma_f32_16x16x32_bf16(vf, pf, accO[ht], 0, 0, 0);
        }
    };

    const int npair = w >> 1;            // last pair index; pair p = tiles 2p, 2p+1
    #pragma unroll
    for (int p = 0; p < 8; p++) {
        if (p <= npair) {                // wave-uniform
            // QK^T (S^T tiles): lane holds (kv = 16*(2p+s)+4g+r, q = rb+i)
            f32x4 sA[2];
            sA[0] = f32x4{0.f, 0.f, 0.f, 0.f};
            sA[1] = f32x4{0.f, 0.f, 0.f, 0.f};
            #pragma unroll
            for (int s = 0; s < 2; s++) {
                const int nt = 2 * p + s;
                if (nt <= w) {           // wave-uniform
                    #pragma unroll
                    for (int ks = 0; ks < 2; ks++) {
                        const bf16x8 kfr = *(const bf16x8*)&Ks[(16 * nt + i) * 64 +
                                (((4 * ks + g) ^ (i & 7)) << 3)];
                        sA[s] = __builtin_amdgcn_mfma_f32_16x16x32_bf16(kfr, qf[ks], sA[s], 0, 0, 0);
                    }
                }
            }
            if (p > 0) PVADD((p - 1) & 1, p - 1);   // pipelined PV of prev pair

            float mt = NEG_INF;
            #pragma unroll
            for (int s = 0; s < 2; s++)
                #pragma unroll
                for (int r = 0; r < 4; r++) {
                    const int kv = 16 * (2 * p + s) + 4 * g + r;
                    const bool ok = (2 * p + s <= w) && (kv <= rb + i);
                    const float v = ok ? sA[s][r] * SCALE_ : NEG_INF;
                    sA[s][r] = v;
                    mt = fmaxf(mt, v);
                }
            mt = fmaxf(mt, __shfl_xor(mt, 16, 64));
            mt = fmaxf(mt, __shfl_xor(mt, 32, 64));

            if (!__all(mt <= mrun + 8.0f)) {        // defer-max (THR=8)
                const float mnew = fmaxf(mrun, mt);
                const float f = __expf(mrun - mnew);
                mrun = mnew; lrun *= f;
                #pragma unroll
                for (int ht = 0; ht < 4; ht++)
                    #pragma unroll
                    for (int r = 0; r < 4; r++) accO[ht][r] *= f;
            }
            #pragma unroll
            for (int s = 0; s < 2; s++) {
                const float p0 = __expf(sA[s][0] - mrun);
                const float p1 = __expf(sA[s][1] - mrun);
                const float p2 = __expf(sA[s][2] - mrun);
                const float p3 = __expf(sA[s][3] - mrun);
                lrun += (p0 + p1) + (p2 + p3);
                union { bf16x4 v; unsigned u[2]; } pk;
                pk.u[0] = cvt_pk_bf16(p0, p1);
                pk.u[1] = cvt_pk_bf16(p2, p3);
                *(bf16x4*)&myP[(p & 1) * 640 + i * 40 + 16 * s + 4 * g] = pk.v;
            }
        }
    }
    PVADD(npair & 1, npair);             // drain last pair

    // final denominator (sum across the 4 g-lanes of column q)
    lrun += __shfl_xor(lrun, 16, 64);
    lrun += __shfl_xor(lrun, 32, 64);
    const float inv = 1.f / lrun;

    // store O^T: lane holds (h = 16ht+4g+r, q = rb+i) -> float4 per ht
    float* orow = out + ((size_t)b * T_ + rb + i) * H_;
    #pragma unroll
    for (int ht = 0; ht < 4; ht++) {
        float4 o;
        o.x = accO[ht][0] * inv;
        o.y = accO[ht][1] * inv;
        o.z = accO[ht][2] * inv;
        o.w = accO[ht][3] * inv;
        *(float4*)&orow[16 * ht + 4 * g] = o;
    }
}

extern "C" void kernel_launch(void* const* d_in, const int* in_sizes, int n_in,
                              void* d_out, int out_size, void* d_ws, size_t ws_size,
                              hipStream_t stream) {
    const float* x  = (const float*)d_in[0];
    const float* Wk = (const float*)d_in[1];
    const float* Wq = (const float*)d_in[2];
    const float* Wv = (const float*)d_in[3];
    float* out = (float*)d_out;
    (void)d_ws; (void)ws_size; (void)in_sizes; (void)n_in; (void)out_size;
    att_head_kernel<<<dim3(B_), dim3(1024), 0, stream>>>(x, Wk, Wq, Wv, out);
}